// Round 8
// baseline (500.615 us; speedup 1.0000x reference)
//
#include <hip/hip_runtime.h>
#include <stdint.h>

#define NBATCH 16
#define HW_ (1 << 20)            // 1024*1024 per batch
#define TPB 256

#define NBPB_H 32                // blocks per batch for hist pass
#define TPB_H 512
#define EPB_H (HW_ / NBPB_H)     // 32768 elements per block
#define ITER_H (EPB_H / (TPB_H * 4)) // 16 float4 per thread

#define NBINS 8192               // fine bins on score_bits >> 12; base 0x3F400
#define FBASE 0x3F400

#define NBPB_F 256               // blocks per batch for main pass
#define FCHUNK (HW_ / NBPB_F)    // 4096 elements per block

#define CAND_CAP 32768           // ambiguous candidates per batch (fine-bin count ~500)
#define LCAP 512                 // per-block LDS candidate capacity
#define TIE_CAP 1024             // exact score-bit duplicates among candidates (expected ~4)
#define CSTR 64                  // u32 stride between per-batch counters (256 B)

typedef float f4v __attribute__((ext_vector_type(4)));

struct BParams {
    unsigned int k;        // n_train
    unsigned int bin1f;    // selected fine bin as raw (score_bits>>12); 0xFFFFFFFF if k==0
    unsigned int r;        // rank remaining within bin1f (k - count_above)
    unsigned int mode;     // 0 = no train, 1 = normal
};

__device__ __forceinline__ unsigned int score_bits(float p, int m) {
    bool correct = (p > 0.5f) == (m == 1);
    float conf = fmaxf(p, 1.0f - p);
    float base = correct ? ((conf > 0.85f) ? 1.0f : 2.0f)
                         : ((conf > 0.85f) ? 4.0f : 3.0f);
    float bonus = (conf - 0.5f) * 0.5f;   // exact in f32
    float s = correct ? (base - bonus) : (base + bonus);
    return __float_as_uint(s);            // positive floats: bit order == value order
}

// Kernel A: per-block slice histograms; last arriver per batch sums slices + finds bin.
__global__ void k_histfind(const float4* __restrict__ pred4, const int4* __restrict__ mask4,
                           unsigned int* __restrict__ slices, unsigned int* __restrict__ doneA,
                           BParams* __restrict__ prm) {
    __shared__ unsigned int lh[NBINS];     // 32 KB
    __shared__ unsigned int cs_[TPB_H + 1];
    __shared__ unsigned int lastFlag;
    int b = blockIdx.x / NBPB_H;
    int blk = blockIdx.x % NBPB_H;
    int t = threadIdx.x;
    for (int i = t; i < NBINS; i += TPB_H) lh[i] = 0;
    __syncthreads();
    int l4base = blk * (EPB_H / 4);
    for (int j = 0; j < ITER_H; j++) {
        int i4l = l4base + j * TPB_H + t;
        size_t g4 = (size_t)b * (HW_ / 4) + i4l;
        float4 p = pred4[g4];
        int4 m = mask4[g4];
        float pa[4] = {p.x, p.y, p.z, p.w};
        int ma[4] = {m.x, m.y, m.z, m.w};
#pragma unroll
        for (int l = 0; l < 4; l++) {
            if (ma[l] != 2) {
                unsigned int sb = score_bits(pa[l], ma[l]);
                int fb = (int)(sb >> 12) - FBASE;
                fb = min(max(fb, 0), NBINS - 1);
                atomicAdd(&lh[fb], 1u);
            }
        }
    }
    __syncthreads();
    unsigned int* sp = slices + (size_t)blockIdx.x * NBINS;
    for (int i = t; i < NBINS; i += TPB_H) sp[i] = lh[i];   // plain coalesced stores
    __syncthreads();
    if (t == 0) {
        __threadfence();   // flush this XCD's L2 (slice data) to coherence point
        unsigned int old = atomicAdd(&doneA[b * CSTR], 1u);
        lastFlag = (old == NBPB_H - 1) ? 1u : 0u;
    }
    __syncthreads();
    if (!lastFlag) return;

    // ---- find: sum 32 slices (coalesced), suffix scan, locate k-th bin ----
    unsigned int acc[NBINS / TPB_H];   // 16
#pragma unroll
    for (int j = 0; j < NBINS / TPB_H; j++) acc[j] = 0;
    const unsigned int* base = slices + (size_t)b * NBPB_H * NBINS;
    for (int s = 0; s < NBPB_H; s++) {
        const unsigned int* spp = base + (size_t)s * NBINS;
#pragma unroll
        for (int j = 0; j < NBINS / TPB_H; j++) acc[j] += spp[j * TPB_H + t];
    }
#pragma unroll
    for (int j = 0; j < NBINS / TPB_H; j++) lh[j * TPB_H + t] = acc[j];
    __syncthreads();
    {   // chunk sums of 16 consecutive bins per thread
        unsigned int gs = 0;
#pragma unroll
        for (int j = 0; j < NBINS / TPB_H; j++) gs += lh[t * (NBINS / TPB_H) + j];
        cs_[t] = gs;
        if (t == 0) cs_[TPB_H] = 0;
    }
    __syncthreads();
    for (int off = 1; off < TPB_H; off <<= 1) {
        unsigned int a = (t + off < TPB_H) ? cs_[t + off] : 0u;
        __syncthreads();
        cs_[t] += a;
        __syncthreads();
    }
    unsigned int n = cs_[0];                                 // total annotated
    unsigned int k = (unsigned int)(int)((float)n * 0.5f);   // astype(f32)*0.5 -> int32
    if (k == 0) {
        if (t == 0) {
            BParams P; P.k = 0; P.bin1f = 0xFFFFFFFFu; P.r = 0; P.mode = 0;
            prm[b] = P;
        }
        return;
    }
    if (cs_[t] >= k && cs_[t + 1] < k) {   // unique boundary chunk
        unsigned int cum = cs_[t + 1];
        for (int j = (NBINS / TPB_H) - 1; j >= 0; j--) {
            unsigned int hb = lh[t * (NBINS / TPB_H) + j];
            if (cum + hb >= k) {
                BParams P;
                P.k = k;
                P.bin1f = (unsigned int)(FBASE + t * (NBINS / TPB_H) + j);
                P.r = k - cum;
                P.mode = 1;
                prm[b] = P;
                break;
            }
            cum += hb;
        }
    }
}

// Kernel B LDS union: main staging vs fixup scratch
struct MainS {
    unsigned int lcode[FCHUNK / 4];
    unsigned int l_idx[LCAP]; unsigned int l_sb[LCAP]; float l_bce[LCAP];
    float red[TPB];
    unsigned int lcnt, gbase;
};
struct FixS {
    unsigned int h[4096]; unsigned int cs_[257];
    unsigned int tie_idx[TIE_CAP]; unsigned int misc[8];
    float red[TPB];
};
union SmemB { MainS m; FixS f; };

// Kernel B: main pass + last-arriver fixup per batch + global-last loss.
__global__ void k_mainall(const float4* __restrict__ pred4, const int4* __restrict__ mask4,
                          const BParams* __restrict__ prm, float* __restrict__ out,
                          unsigned int* __restrict__ doneB, unsigned int* __restrict__ doneC,
                          unsigned int* __restrict__ cand_cnt, double* __restrict__ bsum,
                          unsigned int* __restrict__ cand_idx, unsigned int* __restrict__ cand_sb,
                          float* __restrict__ cand_bce) {
    __shared__ SmemB sm;
    __shared__ unsigned int lastFlag;
    int b = blockIdx.x / NBPB_F;
    int blk = blockIdx.x % NBPB_F;
    int t = threadIdx.x;
    BParams P = prm[b];
    unsigned int target = P.bin1f;
    if (t == 0) sm.m.lcnt = 0;
    __syncthreads();
    float acc = 0.0f;
    int ibase = blk * FCHUNK;
    for (int j = 0; j < FCHUNK / (TPB * 4); j++) {   // 4 iterations
        int v = j * TPB + t;                         // word index [0,1024)
        size_t g4 = (size_t)b * (HW_ / 4) + (ibase / 4) + v;
        float4 p = pred4[g4];
        int4 m = mask4[g4];
        float pa[4] = {p.x, p.y, p.z, p.w};
        int ma[4] = {m.x, m.y, m.z, m.w};
        unsigned int cw = 0;
#pragma unroll
        for (int l = 0; l < 4; l++) {
            bool ann = (ma[l] != 2);
            unsigned int sb = score_bits(pa[l], ma[l]);
            unsigned int fine = sb >> 12;
            bool tr = ann && (fine > target);
            bool amb = ann && (fine == target);
            unsigned int code = (tr ? 1u : 0u) | ((ann && !tr) ? 2u : 0u);
            cw |= code << (8 * l);
            float bce = 0.0f;
            if (tr || amb) {
                float pc = fminf(fmaxf(pa[l], 1e-7f), 1.0f - 1e-7f);
                bce = (ma[l] == 1) ? -__logf(pc) : -__logf(1.0f - pc);
            }
            if (tr) acc += bce;
            if (amb) {
                unsigned int p0 = atomicAdd(&sm.m.lcnt, 1u);  // LDS atomic
                if (p0 < LCAP) {
                    sm.m.l_idx[p0] = (unsigned int)(ibase + v * 4 + l);
                    sm.m.l_sb[p0] = sb;
                    sm.m.l_bce[p0] = bce;
                } else {
                    unsigned int gp = atomicAdd(&cand_cnt[b * CSTR], 1u);
                    if (gp < CAND_CAP) {
                        size_t o = (size_t)b * CAND_CAP + gp;
                        cand_idx[o] = (unsigned int)(ibase + v * 4 + l);
                        cand_sb[o] = sb;
                        cand_bce[o] = bce;
                    }
                }
            }
        }
        sm.m.lcode[v] = cw;   // stride-1 ds_write_b32, conflict-free
    }
    __syncthreads();
    // one global reservation per block, coalesced copy of LDS candidate list
    unsigned int nc = min(sm.m.lcnt, (unsigned int)LCAP);
    if (t == 0 && nc > 0)
        sm.m.gbase = atomicAdd(&cand_cnt[b * CSTR], nc);
    __syncthreads();
    for (unsigned int i = t; i < nc; i += TPB) {
        unsigned int pos = sm.m.gbase + i;
        if (pos < CAND_CAP) {
            size_t o = (size_t)b * CAND_CAP + pos;
            cand_idx[o] = sm.m.l_idx[i];
            cand_sb[o] = sm.m.l_sb[i];
            cand_bce[o] = sm.m.l_bce[i];
        }
    }
    // masks: out[0]=loss, train at out[1..], holdout next
    float* trout = out + 1;
    float* hoout = out + 1 + (size_t)NBATCH * HW_;
    size_t Gbase = (size_t)b * HW_ + (size_t)ibase;
    for (int v = t; v < FCHUNK / 4 - 1; v += TPB) {
        unsigned int w0 = sm.m.lcode[v];
        unsigned int w1 = sm.m.lcode[v + 1];
        unsigned int c0 = (w0 >> 24) & 0xFFu;
        unsigned int c1 = w1 & 0xFFu;
        unsigned int c2 = (w1 >> 8) & 0xFFu;
        unsigned int c3 = (w1 >> 16) & 0xFFu;
        int e = 3 + 4 * v;
        f4v tv = { (float)(c0 & 1u), (float)(c1 & 1u), (float)(c2 & 1u), (float)(c3 & 1u) };
        f4v hv = { (float)((c0 >> 1) & 1u), (float)((c1 >> 1) & 1u),
                   (float)((c2 >> 1) & 1u), (float)((c3 >> 1) & 1u) };
        __builtin_nontemporal_store(tv, (f4v*)(trout + Gbase + e));
        __builtin_nontemporal_store(hv, (f4v*)(hoout + Gbase + e));
    }
    if (t < 3) {
        unsigned int c = (sm.m.lcode[0] >> (8 * t)) & 0xFFu;
        trout[Gbase + t] = (float)(c & 1u);
        hoout[Gbase + t] = (float)((c >> 1) & 1u);
    }
    if (t == 3) {
        unsigned int c = (sm.m.lcode[FCHUNK / 4 - 1] >> 24) & 0xFFu;
        trout[Gbase + FCHUNK - 1] = (float)(c & 1u);
        hoout[Gbase + FCHUNK - 1] = (float)((c >> 1) & 1u);
    }
    sm.m.red[t] = acc;
    __syncthreads();
    for (int off = TPB / 2; off > 0; off >>= 1) {
        if (t < off) sm.m.red[t] += sm.m.red[t + off];
        __syncthreads();
    }
    if (t == 0) {
        if (sm.m.red[0] != 0.0f) atomicAdd(&bsum[b], (double)sm.m.red[0]);
        __threadfence();
        unsigned int old = atomicAdd(&doneB[b * CSTR], 1u);
        lastFlag = (old == NBPB_F - 1) ? 1u : 0u;
    }
    __syncthreads();
    if (!lastFlag) return;

    // ---------------- fixup (last arriver of batch b) ----------------
    if (P.mode != 0) {
        unsigned int C = cand_cnt[b * CSTR];
        if (C > CAND_CAP) C = CAND_CAP;
        const unsigned int* ci = cand_idx + (size_t)b * CAND_CAP;
        const unsigned int* cs = cand_sb + (size_t)b * CAND_CAP;
        const float* cb = cand_bce + (size_t)b * CAND_CAP;
        for (int i = t; i < 4096; i += TPB) sm.f.h[i] = 0;
        if (t < 8) sm.f.misc[t] = (t == 4) ? 0xFFFFFFFFu : 0u;
        __syncthreads();
        for (unsigned int i = t; i < C; i += TPB)
            atomicAdd(&sm.f.h[cs[i] & 0xFFFu], 1u);
        __syncthreads();
        {
            unsigned int gs = 0;
#pragma unroll
            for (int j = 0; j < 16; j++) gs += sm.f.h[t * 16 + j];
            sm.f.cs_[t] = gs;
            if (t == 0) sm.f.cs_[256] = 0;
        }
        __syncthreads();
        for (int off = 1; off < 256; off <<= 1) {
            unsigned int a = (t + off < 256) ? sm.f.cs_[t + off] : 0u;
            __syncthreads();
            sm.f.cs_[t] += a;
            __syncthreads();
        }
        if (sm.f.cs_[t] >= P.r && sm.f.cs_[t + 1] < P.r) {
            unsigned int cum = sm.f.cs_[t + 1];
            for (int j = 15; j >= 0; j--) {
                unsigned int hb = sm.f.h[t * 16 + j];
                if (cum + hb >= P.r) {
                    unsigned int T = P.r - cum;
                    sm.f.misc[0] = (unsigned int)(t * 16 + j);
                    sm.f.misc[1] = T;
                    sm.f.misc[2] = (T == hb) ? 1u : 0u;
                    break;
                }
                cum += hb;
            }
        }
        __syncthreads();
        unsigned int vstar = sm.f.misc[0], T = sm.f.misc[1];
        bool allTies = (sm.f.misc[2] != 0);
        unsigned int idxcut;
        if (allTies) {
            idxcut = 0xFFFFFFFFu;
        } else {
            for (unsigned int i = t; i < C; i += TPB) {
                if ((cs[i] & 0xFFFu) == vstar) {
                    unsigned int p = atomicAdd(&sm.f.misc[3], 1u);
                    if (p < TIE_CAP) sm.f.tie_idx[p] = ci[i];
                }
            }
            __syncthreads();
            unsigned int E2 = sm.f.misc[3];
            if (E2 > TIE_CAP) E2 = TIE_CAP;
            for (unsigned int i = t; i < E2; i += TPB) {
                unsigned int vi = sm.f.tie_idx[i];
                unsigned int cnt = 0;
                for (unsigned int j = 0; j < E2; j++)
                    cnt += (sm.f.tie_idx[j] < vi) ? 1u : 0u;
                if (cnt == T - 1) sm.f.misc[4] = vi;  // T-th smallest tie index
            }
            __syncthreads();
            idxcut = sm.f.misc[4];
        }
        float facc = 0.0f;
        size_t basee = (size_t)b * HW_;
        for (unsigned int i = t; i < C; i += TPB) {
            unsigned int low = cs[i] & 0xFFFu;
            bool tr = (low > vstar) || (low == vstar && ci[i] <= idxcut);
            if (tr) {
                trout[basee + ci[i]] = 1.0f;
                hoout[basee + ci[i]] = 0.0f;
                facc += cb[i];
            }
        }
        sm.f.red[t] = facc;
        __syncthreads();
        for (int off = TPB / 2; off > 0; off >>= 1) {
            if (t < off) sm.f.red[t] += sm.f.red[t + off];
            __syncthreads();
        }
        if (t == 0 && sm.f.red[0] != 0.0f) atomicAdd(&bsum[b], (double)sm.f.red[0]);
    }
    // ---------------- loss (global last arriver) ----------------
    if (t == 0) {
        __threadfence();
        unsigned int old2 = atomicAdd(doneC, 1u);
        if (old2 == NBATCH - 1) {
            double num = 0.0;
            unsigned long long den = 0;
            for (int b2 = 0; b2 < NBATCH; b2++) {
                num += atomicAdd(&bsum[b2], 0.0);   // device-scope read
                den += prm[b2].k;
            }
            float denf = (float)den + 1e-7f;
            out[0] = (float)num / denf;
        }
    }
}

extern "C" void kernel_launch(void* const* d_in, const int* in_sizes, int n_in,
                              void* d_out, int out_size, void* d_ws, size_t ws_size,
                              hipStream_t stream) {
    const float4* pred4 = (const float4*)d_in[0];
    const int4* mask4 = (const int4*)d_in[1];
    float* out = (float*)d_out;

    // ws layout: [0,32KB) zeroed counter region | slices | prm | cand arrays
    unsigned int* ctr = (unsigned int*)d_ws;
    unsigned int* doneA = ctr;                      // stride CSTR per batch
    unsigned int* doneB = ctr + 1024;               // stride CSTR per batch
    unsigned int* cand_cnt = ctr + 2048;            // stride CSTR per batch
    unsigned int* doneC = ctr + 3072;               // single
    double* bsum = (double*)((char*)d_ws + 16384);  // 16 doubles
    unsigned int* slices = (unsigned int*)((char*)d_ws + 32768);  // 16*32*8192 u32 = 16 MB
    BParams* prm = (BParams*)(slices + (size_t)NBATCH * NBPB_H * NBINS);
    unsigned int* cand_idx = (unsigned int*)(prm + NBATCH);       // 16*32768
    unsigned int* cand_sb = cand_idx + NBATCH * CAND_CAP;
    float* cand_bce = (float*)(cand_sb + NBATCH * CAND_CAP);

    hipMemsetAsync(d_ws, 0, 32768, stream);
    k_histfind<<<dim3(NBATCH * NBPB_H), dim3(TPB_H), 0, stream>>>(pred4, mask4, slices,
                                                                  doneA, prm);
    k_mainall<<<dim3(NBATCH * NBPB_F), dim3(TPB), 0, stream>>>(pred4, mask4, prm, out,
                                                               doneB, doneC, cand_cnt, bsum,
                                                               cand_idx, cand_sb, cand_bce);
}

// Round 9
// 290.081 us; speedup vs baseline: 1.7258x; 1.7258x over previous
//
#include <hip/hip_runtime.h>
#include <stdint.h>

#define NBATCH 16
#define HW_ (1 << 20)            // 1024*1024 per batch
#define TPB 256

#define NBPB_H 64                // blocks per batch for hist pass
#define EPB_H (HW_ / NBPB_H)     // 16384 elements per block
#define ITER_H (EPB_H / (TPB * 4)) // 16 float4 per thread

#define NBINS 8192               // fine bins on score_bits >> 12; base 0x3F400
#define FBASE 0x3F400

#define NBPB_F 256               // blocks per batch for main pass
#define FCHUNK (HW_ / NBPB_F)    // 4096 elements per block

#define CAND_CAP 32768           // ambiguous candidates per batch (fine-bin count ~500)
#define LCAP 512                 // per-block LDS candidate capacity
#define TIE_CAP 4096
#define CSTR 64                  // u32 stride between per-batch counters (256 B)

typedef float f4v __attribute__((ext_vector_type(4)));

struct BParams {
    unsigned int k;        // n_train
    unsigned int bin1f;    // selected fine bin as raw (score_bits>>12); 0xFFFFFFFF if k==0
    unsigned int r;        // rank remaining within bin1f (k - count_above)
    unsigned int mode;     // 0 = no train, 1 = normal
};

__device__ __forceinline__ unsigned int score_bits(float p, int m) {
    bool correct = (p > 0.5f) == (m == 1);
    float conf = fmaxf(p, 1.0f - p);
    float base = correct ? ((conf > 0.85f) ? 1.0f : 2.0f)
                         : ((conf > 0.85f) ? 4.0f : 3.0f);
    float bonus = (conf - 0.5f) * 0.5f;   // exact in f32
    float s = correct ? (base - bonus) : (base + bonus);
    return __float_as_uint(s);            // positive floats: bit order == value order
}

// Pass 1: 8192-bin fine histogram on (score_bits>>12) - FBASE. Single LDS hist.
__global__ void k_hist1(const float4* __restrict__ pred4, const int4* __restrict__ mask4,
                        unsigned int* __restrict__ hist1) {
    __shared__ unsigned int lh[NBINS];
    int b = blockIdx.x / NBPB_H;
    int blk = blockIdx.x % NBPB_H;
    for (int i = threadIdx.x; i < NBINS; i += TPB) lh[i] = 0;
    __syncthreads();
    int l4base = blk * (EPB_H / 4);
    for (int j = 0; j < ITER_H; j++) {
        int i4l = l4base + j * TPB + threadIdx.x;
        size_t g4 = (size_t)b * (HW_ / 4) + i4l;
        float4 p = pred4[g4];
        int4 m = mask4[g4];
        float pa[4] = {p.x, p.y, p.z, p.w};
        int ma[4] = {m.x, m.y, m.z, m.w};
#pragma unroll
        for (int l = 0; l < 4; l++) {
            if (ma[l] != 2) {
                unsigned int sb = score_bits(pa[l], ma[l]);
                int fb = (int)(sb >> 12) - FBASE;
                fb = min(max(fb, 0), NBINS - 1);
                atomicAdd(&lh[fb], 1u);
            }
        }
    }
    __syncthreads();
    for (int i = threadIdx.x; i < NBINS; i += TPB) {
        unsigned int v = lh[i];
        if (v) atomicAdd(&hist1[b * NBINS + i], v);
    }
}

// Find fine bin containing the k-th largest; k derived from hist total.
__global__ void k_find1(const unsigned int* __restrict__ hist1, BParams* prm) {
    int b = blockIdx.x;
    int t = threadIdx.x;
    __shared__ unsigned int cs_[257];
    const unsigned int* h = hist1 + (size_t)b * NBINS;
    // chunk sums: thread t sums bins [32t, 32t+32) with uint4 loads
    {
        const uint4* h4 = (const uint4*)(h + t * 32);
        unsigned int s = 0;
#pragma unroll
        for (int j = 0; j < 8; j++) { uint4 v = h4[j]; s += v.x + v.y + v.z + v.w; }
        cs_[t] = s;
        if (t == 0) cs_[256] = 0;
    }
    __syncthreads();
    for (int off = 1; off < 256; off <<= 1) {
        unsigned int a = (t + off < 256) ? cs_[t + off] : 0u;
        __syncthreads();
        cs_[t] += a;
        __syncthreads();
    }
    unsigned int n = cs_[0];                       // total annotated
    unsigned int k = (unsigned int)(int)((float)n * 0.5f);  // astype(f32)*0.5 -> int32
    if (k == 0) {
        if (t == 0) {
            BParams P;
            P.k = 0; P.bin1f = 0xFFFFFFFFu; P.r = 0; P.mode = 0;
            prm[b] = P;
        }
        return;
    }
    if (cs_[t] >= k && cs_[t + 1] < k) {           // unique boundary chunk
        unsigned int cum = cs_[t + 1];
        for (int j = 31; j >= 0; j--) {
            unsigned int hb = h[t * 32 + j];
            if (cum + hb >= k) {
                BParams P;
                P.k = k;
                P.bin1f = (unsigned int)(FBASE + t * 32 + j);
                P.r = k - cum;
                P.mode = 1;
                prm[b] = P;
                break;
            }
            cum += hb;
        }
    }
}

// Main fused pass: byte-code mask staging (stride-1 LDS, no conflicts), BCE for
// definite-train, per-block LDS candidate staging, one global atomic per block.
__global__ void k_main(const float4* __restrict__ pred4, const int4* __restrict__ mask4,
                       const BParams* __restrict__ prm, float* __restrict__ out,
                       float* __restrict__ partials, unsigned int* __restrict__ cand_cnt,
                       unsigned int* __restrict__ cand_idx, unsigned int* __restrict__ cand_sb,
                       float* __restrict__ cand_bce) {
    int b = blockIdx.x / NBPB_F;
    int blk = blockIdx.x % NBPB_F;
    BParams P = prm[b];
    unsigned int target = P.bin1f;
    __shared__ unsigned int lcode[FCHUNK / 4];   // 2-bit code per elem, 4 per u32
    __shared__ float red[TPB];
    __shared__ unsigned int l_idx[LCAP];
    __shared__ unsigned int l_sb[LCAP];
    __shared__ float l_bce[LCAP];
    __shared__ unsigned int lcnt;
    __shared__ unsigned int gbase;
    if (threadIdx.x == 0) lcnt = 0;
    __syncthreads();
    float acc = 0.0f;
    int ibase = blk * FCHUNK;
    for (int j = 0; j < FCHUNK / (TPB * 4); j++) {   // 4 iterations
        int v = j * TPB + threadIdx.x;               // word index [0,1024)
        size_t g4 = (size_t)b * (HW_ / 4) + (ibase / 4) + v;
        float4 p = pred4[g4];
        int4 m = mask4[g4];
        float pa[4] = {p.x, p.y, p.z, p.w};
        int ma[4] = {m.x, m.y, m.z, m.w};
        unsigned int cw = 0;
#pragma unroll
        for (int l = 0; l < 4; l++) {
            bool ann = (ma[l] != 2);
            unsigned int sb = score_bits(pa[l], ma[l]);
            unsigned int fine = sb >> 12;
            bool tr = ann && (fine > target);
            bool amb = ann && (fine == target);
            unsigned int code = (tr ? 1u : 0u) | ((ann && !tr) ? 2u : 0u);
            cw |= code << (8 * l);
            float bce = 0.0f;
            if (tr || amb) {
                float pc = fminf(fmaxf(pa[l], 1e-7f), 1.0f - 1e-7f);
                bce = (ma[l] == 1) ? -__logf(pc) : -__logf(1.0f - pc);
            }
            if (tr) acc += bce;
            if (amb) {
                unsigned int p0 = atomicAdd(&lcnt, 1u);  // LDS atomic
                if (p0 < LCAP) {
                    l_idx[p0] = (unsigned int)(ibase + v * 4 + l);
                    l_sb[p0] = sb;
                    l_bce[p0] = bce;
                } else {
                    unsigned int gp = atomicAdd(&cand_cnt[b * CSTR], 1u);
                    if (gp < CAND_CAP) {
                        size_t o = (size_t)b * CAND_CAP + gp;
                        cand_idx[o] = (unsigned int)(ibase + v * 4 + l);
                        cand_sb[o] = sb;
                        cand_bce[o] = bce;
                    }
                }
            }
        }
        lcode[v] = cw;   // stride-1 ds_write_b32, conflict-free
    }
    __syncthreads();
    // one global reservation per block, coalesced copy of LDS candidate list
    unsigned int n = min(lcnt, (unsigned int)LCAP);
    if (threadIdx.x == 0 && n > 0)
        gbase = atomicAdd(&cand_cnt[b * CSTR], n);
    __syncthreads();
    for (unsigned int i = threadIdx.x; i < n; i += TPB) {
        unsigned int pos = gbase + i;
        if (pos < CAND_CAP) {
            size_t o = (size_t)b * CAND_CAP + pos;
            cand_idx[o] = l_idx[i];
            cand_sb[o] = l_sb[i];
            cand_bce[o] = l_bce[i];
        }
    }
    // out layout: out[0]=loss, train at out[1 .. 1+16M), holdout next.
    float* trout = out + 1;
    float* hoout = out + 1 + (size_t)NBATCH * HW_;
    size_t Gbase = (size_t)b * HW_ + (size_t)ibase;
    // aligned float4 stores covering local elems [3, 4095)
    for (int v = threadIdx.x; v < FCHUNK / 4 - 1; v += TPB) {
        unsigned int w0 = lcode[v];
        unsigned int w1 = lcode[v + 1];
        unsigned int c0 = (w0 >> 24) & 0xFFu;
        unsigned int c1 = w1 & 0xFFu;
        unsigned int c2 = (w1 >> 8) & 0xFFu;
        unsigned int c3 = (w1 >> 16) & 0xFFu;
        int e = 3 + 4 * v;
        f4v tv = { (float)(c0 & 1u), (float)(c1 & 1u), (float)(c2 & 1u), (float)(c3 & 1u) };
        f4v hv = { (float)((c0 >> 1) & 1u), (float)((c1 >> 1) & 1u),
                   (float)((c2 >> 1) & 1u), (float)((c3 >> 1) & 1u) };
        __builtin_nontemporal_store(tv, (f4v*)(trout + Gbase + e));
        __builtin_nontemporal_store(hv, (f4v*)(hoout + Gbase + e));
    }
    if (threadIdx.x < 3) {   // head elems 0,1,2
        unsigned int c = (lcode[0] >> (8 * threadIdx.x)) & 0xFFu;
        trout[Gbase + threadIdx.x] = (float)(c & 1u);
        hoout[Gbase + threadIdx.x] = (float)((c >> 1) & 1u);
    }
    if (threadIdx.x == 3) {  // tail elem 4095
        unsigned int c = (lcode[FCHUNK / 4 - 1] >> 24) & 0xFFu;
        trout[Gbase + FCHUNK - 1] = (float)(c & 1u);
        hoout[Gbase + FCHUNK - 1] = (float)((c >> 1) & 1u);
    }
    red[threadIdx.x] = acc;
    __syncthreads();
    for (int off = TPB / 2; off > 0; off >>= 1) {
        if (threadIdx.x < off) red[threadIdx.x] += red[threadIdx.x + off];
        __syncthreads();
    }
    if (threadIdx.x == 0) partials[blockIdx.x] = red[0];
}

// Fixup + loss merged: 16 blocks. Each does its batch's exact select/scatter;
// the last arriver (16 fences total, cheap) computes the final loss.
__global__ void k_fixuploss(const unsigned int* __restrict__ cand_cnt,
                            const unsigned int* __restrict__ cand_idx,
                            const unsigned int* __restrict__ cand_sb,
                            const float* __restrict__ cand_bce,
                            const BParams* __restrict__ prm, float* __restrict__ out,
                            float* __restrict__ tie_partials,
                            const float* __restrict__ partials,
                            unsigned int* __restrict__ doneC) {
    int b = blockIdx.x;
    int t = threadIdx.x;
    __shared__ unsigned int h[4096];
    __shared__ unsigned int cs_[257];
    __shared__ unsigned int tie_idx[TIE_CAP];
    __shared__ unsigned int misc[8];  // [0]=v* [1]=T [2]=allTies [3]=tieCnt [4]=idxcut
    __shared__ float red[TPB];
    __shared__ unsigned int lastFlag;
    BParams P = prm[b];
    if (P.mode != 0) {
        unsigned int C = cand_cnt[b * CSTR];
        if (C > CAND_CAP) C = CAND_CAP;
        const unsigned int* ci = cand_idx + (size_t)b * CAND_CAP;
        const unsigned int* cs = cand_sb + (size_t)b * CAND_CAP;
        const float* cb = cand_bce + (size_t)b * CAND_CAP;
        for (int i = t; i < 4096; i += TPB) h[i] = 0;
        if (t < 8) misc[t] = (t == 4) ? 0xFFFFFFFFu : 0u;
        __syncthreads();
        // exact 4096-bin hist on low-12 bits
        for (unsigned int i = t; i < C; i += TPB)
            atomicAdd(&h[cs[i] & 0xFFFu], 1u);
        __syncthreads();
        {
            unsigned int gs = 0;
#pragma unroll
            for (int j = 0; j < 16; j++) gs += h[t * 16 + j];
            cs_[t] = gs;
            if (t == 0) cs_[256] = 0;
        }
        __syncthreads();
        for (int off = 1; off < 256; off <<= 1) {
            unsigned int a = (t + off < 256) ? cs_[t + off] : 0u;
            __syncthreads();
            cs_[t] += a;
            __syncthreads();
        }
        if (cs_[t] >= P.r && cs_[t + 1] < P.r) {
            unsigned int cum = cs_[t + 1];
            for (int j = 15; j >= 0; j--) {
                unsigned int hb = h[t * 16 + j];
                if (cum + hb >= P.r) {
                    unsigned int T = P.r - cum;
                    misc[0] = (unsigned int)(t * 16 + j);
                    misc[1] = T;
                    misc[2] = (T == hb) ? 1u : 0u;
                    break;
                }
                cum += hb;
            }
        }
        __syncthreads();
        unsigned int vstar = misc[0], T = misc[1];
        bool allTies = (misc[2] != 0);
        unsigned int idxcut;
        if (allTies) {
            idxcut = 0xFFFFFFFFu;
        } else {
            for (unsigned int i = t; i < C; i += TPB) {
                if ((cs[i] & 0xFFFu) == vstar) {
                    unsigned int p = atomicAdd(&misc[3], 1u);
                    if (p < TIE_CAP) tie_idx[p] = ci[i];
                }
            }
            __syncthreads();
            unsigned int E2 = misc[3];
            if (E2 > TIE_CAP) E2 = TIE_CAP;
            for (unsigned int i = t; i < E2; i += TPB) {
                unsigned int vi = tie_idx[i];
                unsigned int cnt = 0;
                for (unsigned int j = 0; j < E2; j++) cnt += (tie_idx[j] < vi) ? 1u : 0u;
                if (cnt == T - 1) misc[4] = vi;  // T-th smallest tie index
            }
            __syncthreads();
            idxcut = misc[4];
        }
        // scatter-correct masks + tie BCE
        float acc = 0.0f;
        float* trout = out + 1;
        float* hoout = out + 1 + (size_t)NBATCH * HW_;
        size_t base = (size_t)b * HW_;
        for (unsigned int i = t; i < C; i += TPB) {
            unsigned int low = cs[i] & 0xFFFu;
            bool tr = (low > vstar) || (low == vstar && ci[i] <= idxcut);
            if (tr) {
                trout[base + ci[i]] = 1.0f;
                hoout[base + ci[i]] = 0.0f;
                acc += cb[i];
            }
        }
        red[t] = acc;
        __syncthreads();
        for (int off = TPB / 2; off > 0; off >>= 1) {
            if (t < off) red[t] += red[t + off];
            __syncthreads();
        }
        if (t == 0) tie_partials[b] = red[0];
    } else {
        if (t == 0) tie_partials[b] = 0.0f;
    }
    // ---- last arriver (of 16) computes the loss ----
    if (t == 0) {
        __threadfence();
        lastFlag = (atomicAdd(doneC, 1u) == NBATCH - 1) ? 1u : 0u;
    }
    __syncthreads();
    if (!lastFlag) return;
    {
        __shared__ double dred[TPB];
        double s = 0.0;
        for (int i = t; i < NBATCH * NBPB_F; i += TPB) s += (double)partials[i];
        if (t < NBATCH) s += (double)tie_partials[t];
        dred[t] = s;
        __syncthreads();
        for (int off = TPB / 2; off > 0; off >>= 1) {
            if (t < off) dred[t] += dred[t + off];
            __syncthreads();
        }
        if (t == 0) {
            unsigned long long den = 0;
            for (int b2 = 0; b2 < NBATCH; b2++) den += prm[b2].k;
            float denf = (float)den + 1e-7f;
            out[0] = (float)dred[0] / denf;
        }
    }
}

extern "C" void kernel_launch(void* const* d_in, const int* in_sizes, int n_in,
                              void* d_out, int out_size, void* d_ws, size_t ws_size,
                              hipStream_t stream) {
    const float4* pred4 = (const float4*)d_in[0];
    const int4* mask4 = (const int4*)d_in[1];
    float* out = (float*)d_out;

    // workspace layout (u32 words); zeroed region first: hist1 | cand_cnt(padded) | doneC
    unsigned int* hist1 = (unsigned int*)d_ws;                  // 16*8192
    unsigned int* cand_cnt = hist1 + NBATCH * NBINS;            // 16*CSTR
    unsigned int* doneC = cand_cnt + NBATCH * CSTR;             // 1 (pad 64)
    BParams* prm = (BParams*)(doneC + 64);                      // 16 structs
    float* partials = (float*)(prm + NBATCH);                   // 16*256
    float* tie_partials = partials + NBATCH * NBPB_F;           // 16
    unsigned int* cand_idx = (unsigned int*)(tie_partials + NBATCH);  // 16*32768
    unsigned int* cand_sb = cand_idx + NBATCH * CAND_CAP;
    float* cand_bce = (float*)(cand_sb + NBATCH * CAND_CAP);

    size_t zero_bytes = (size_t)(NBATCH * NBINS + NBATCH * CSTR + 64) * 4;
    hipMemsetAsync(d_ws, 0, zero_bytes, stream);

    k_hist1<<<dim3(NBATCH * NBPB_H), dim3(TPB), 0, stream>>>(pred4, mask4, hist1);
    k_find1<<<dim3(NBATCH), dim3(TPB), 0, stream>>>(hist1, prm);
    k_main<<<dim3(NBATCH * NBPB_F), dim3(TPB), 0, stream>>>(pred4, mask4, prm, out, partials,
                                                            cand_cnt, cand_idx, cand_sb, cand_bce);
    k_fixuploss<<<dim3(NBATCH), dim3(TPB), 0, stream>>>(cand_cnt, cand_idx, cand_sb, cand_bce,
                                                        prm, out, tie_partials, partials, doneC);
}